// Round 3
// baseline (228.333 us; speedup 1.0000x reference)
//
#include <hip/hip_runtime.h>
#include <stdint.h>

typedef __attribute__((ext_vector_type(8))) short bf16x8;
typedef __attribute__((ext_vector_type(4))) short bf16x4;
typedef __attribute__((ext_vector_type(4))) float f32x4;

#define WAVES 4
#define R_STRIDE 72                    // shorts; 144 B rows (16B aligned)
#define A_STRIDE 40                    // shorts; 80 B rows (16B aligned)
#define R_LDS_SHORTS (32 * R_STRIDE)   // 2304
#define A_LDS_SHORTS (32 * A_STRIDE)   // 1280
#define WAVE_LDS (R_LDS_SHORTS + A_LDS_SHORTS)  // 3584 shorts = 7168 B per wave
#define VB_STRIDE 68                   // padded fp32 row stride for reduction buffers
#define NITER 4                        // 4 iters x 4 waves x 32 rows = 512 rows (quarter of N)
#define WS_STRIDE 2080                 // floats per partial: 2048 v + 32 suma (8320 B, 16B-aligned)

static __device__ __forceinline__ unsigned short f2bf(float f) {
    union { float f; unsigned int i; } x; x.f = f;
    unsigned int i = x.i;
    return (unsigned short)((i + 0x7FFFu + ((i >> 16) & 1u)) >> 16);  // RNE
}

static __device__ __forceinline__ bf16x8 cvt8(float4 a, float4 b) {
    bf16x8 r;
    r[0] = (short)f2bf(a.x); r[1] = (short)f2bf(a.y);
    r[2] = (short)f2bf(a.z); r[3] = (short)f2bf(a.w);
    r[4] = (short)f2bf(b.x); r[5] = (short)f2bf(b.y);
    r[6] = (short)f2bf(b.z); r[7] = (short)f2bf(b.w);
    return r;
}

// Sum across the 16 lanes of a DPP row (all lanes end with the total).
// VALU-pipe rotation reduction: row_ror:8,4,2,1  (0x128,0x124,0x122,0x121).
static __device__ __forceinline__ float row_sum16(float x) {
    union fi { float f; int i; };
    fi a, b; a.f = x;
    b.i = __builtin_amdgcn_mov_dpp(a.i, 0x128, 0xf, 0xf, false); a.f += b.f;
    b.i = __builtin_amdgcn_mov_dpp(a.i, 0x124, 0xf, 0xf, false); a.f += b.f;
    b.i = __builtin_amdgcn_mov_dpp(a.i, 0x122, 0xf, 0xf, false); a.f += b.f;
    b.i = __builtin_amdgcn_mov_dpp(a.i, 0x121, 0xf, 0xf, false); a.f += b.f;
    return a.f;
}

// r_lds bank swizzle: logical (n, c) -> short index n*R_STRIDE + (c ^ ((n>>3&3)<<4)).
// Staging writes stay 16B-aligned b128 (XOR permutes 16-elem column groups);
// GEMM2's gather (fixed j,ct: lanes quad,l15) hits banks (ct^quad)*8 + l15/2
// -> all 32 banks, 2 lanes/bank = conflict-free.

// Kernel 1: each block handles a QUARTER of the N range of one m
// (grid 1024 = 4 blocks/CU). 256-thread blocks so __launch_bounds__'s 2nd
// arg means the SAME register budget under BOTH interpretations:
//   CUDA sem (min blocks/CU=4): 4 blk x 4 waves = 16 waves/CU = 4/SIMD -> 128 VGPR
//   HIP  sem (min waves/EU=4):  4 waves/EU                      -> 128 VGPR
// Round-1's (512,4) decoded as CUDA sem = 8 waves/SIMD = 64 VGPR and spilled
// ~69 MB/dispatch; amdgpu_waves_per_eu(4,4) was silently ignored (round 2,
// still 64). Load->cvt is fused per (s,cc) so the fp32 tile never holds 32
// live VGPRs; peak live set ~105 < 128.
__global__ __launch_bounds__(256, 4)
void netvlad_partial(const float* __restrict__ R,
                     const float* __restrict__ W,
                     const float* __restrict__ bias,
                     float* __restrict__ ws)
{
    __shared__ short smem[WAVES * WAVE_LDS];   // 28672 B; reused as fp32 reduction bufs
    __shared__ float suma_buf[2][32];

    const int tid  = threadIdx.x;
    const int wave = tid >> 6;
    const int lane = tid & 63;
    const int l15  = lane & 15;
    const int quad = lane >> 4;
    const int bid  = blockIdx.x;
    const int m    = bid >> 2;
    const int h    = bid & 3;

    short* r_lds = smem + wave * WAVE_LDS;
    short* a_lds = r_lds + R_LDS_SHORTS;

    const float* Rm = R + ((size_t)m * 2048 + (size_t)h * 512) * 64;

    // W fragments (B-operand of GEMM1): lane reads W row (kt*16+l15),
    // cols cc*32+quad*8..+7 : two float4 loads, convert to bf16.
    bf16x8 wf[2][2];
#pragma unroll
    for (int kt = 0; kt < 2; ++kt)
#pragma unroll
        for (int cc = 0; cc < 2; ++cc) {
            const float* wp = W + (kt*16 + l15)*64 + cc*32 + quad*8;
            wf[kt][cc] = cvt8(*(const float4*)wp, *(const float4*)(wp + 4));
        }

    float bval[2];
    bval[0] = bias[l15];
    bval[1] = bias[16 + l15];

    f32x4 acc[2][4];   // v accumulator tiles [ktile][ctile], D-layout
#pragma unroll
    for (int kt = 0; kt < 2; ++kt)
#pragma unroll
        for (int ct = 0; ct < 4; ++ct)
            acc[kt][ct] = (f32x4){0.f, 0.f, 0.f, 0.f};
    float suma[2] = {0.f, 0.f};

#pragma unroll
    for (int it = 0; it < NITER; ++it) {
        const int n0 = it * (WAVES * 32) + wave * 32;

        // load + convert + stage, fused per (s,cc) so fp32 data dies fast
        bf16x8 af[2][2];
#pragma unroll
        for (int s = 0; s < 2; ++s) {
            const int g = (s*2 + (l15 >> 3)) & 3;          // (n>>3)&3 for n=s*16+l15
#pragma unroll
            for (int cc = 0; cc < 2; ++cc) {
                const float* rp = Rm + (size_t)(n0 + s*16 + l15)*64 + cc*32 + quad*8;
                const float4 x0 = *(const float4*)rp;
                const float4 x1 = *(const float4*)(rp + 4);
                af[s][cc] = cvt8(x0, x1);
                const int c0s = (cc*32 + quad*8) ^ (g << 4);
                *(bf16x8*)(r_lds + (s*16 + l15)*R_STRIDE + c0s) = af[s][cc];
            }
        }

        // GEMM1: logits (32 rows x 32 k), 8 MFMAs
        f32x4 d1[2][2];
#pragma unroll
        for (int s = 0; s < 2; ++s)
#pragma unroll
            for (int kt = 0; kt < 2; ++kt) {
                f32x4 d = (f32x4){0.f, 0.f, 0.f, 0.f};
                d = __builtin_amdgcn_mfma_f32_16x16x32_bf16(af[s][0], wf[kt][0], d, 0, 0, 0);
                d = __builtin_amdgcn_mfma_f32_16x16x32_bf16(af[s][1], wf[kt][1], d, 0, 0, 0);
                d1[s][kt] = d;
            }

        // softmax over k (row = s*16 + quad*4 + r, k = kt*16 + l15)
#pragma unroll
        for (int s = 0; s < 2; ++s) {
            bf16x4 p0, p1;
            float a0s = 0.f, a1s = 0.f;
#pragma unroll
            for (int r = 0; r < 4; ++r) {
                float l0 = d1[s][0][r] + bval[0];
                float l1 = d1[s][1][r] + bval[1];
                float e0 = __expf(l0);
                float e1 = __expf(l1);
                float ss = row_sum16(e0 + e1);             // VALU DPP, off the LDS pipe
                float rs = __builtin_amdgcn_rcpf(ss);
                float a0 = e0 * rs, a1 = e1 * rs;
                a0s += a0; a1s += a1;
                p0[r] = (short)f2bf(a0);
                p1[r] = (short)f2bf(a1);
            }
            suma[0] += a0s; suma[1] += a1s;
            // a_lds[k][n] (n contiguous): 4 consecutive n per lane -> 8 B write
            *(bf16x4*)(a_lds + l15*A_STRIDE        + s*16 + quad*4) = p0;
            *(bf16x4*)(a_lds + (16 + l15)*A_STRIDE + s*16 + quad*4) = p1;
        }

        // A2 fragments: A[m=k][kdim=n] -> contiguous 16 B from a_lds
        bf16x8 a2[2];
#pragma unroll
        for (int kt = 0; kt < 2; ++kt)
            a2[kt] = *(bf16x8*)(a_lds + (kt*16 + l15)*A_STRIDE + quad*8);

        // GEMM2: v += a^T r ; B[kdim=n][col=c] gathered from swizzled r_lds.
        // element (n=quad*8+j, c=ct*16+l15) lives at n*R_STRIDE + (ct^quad)*16 + l15
#pragma unroll
        for (int ct = 0; ct < 4; ++ct) {
            const short* bp = r_lds + (quad*8)*R_STRIDE + ((ct ^ quad) << 4) + l15;
            bf16x8 b2;
#pragma unroll
            for (int j = 0; j < 8; ++j)
                b2[j] = bp[j*R_STRIDE];
#pragma unroll
            for (int kt = 0; kt < 2; ++kt)
                acc[kt][ct] = __builtin_amdgcn_mfma_f32_16x16x32_bf16(a2[kt], b2, acc[kt][ct], 0, 0, 0);
        }
    }

    // suma held per-lane for k = l15 (+16): fold the 4 quads together
#pragma unroll
    for (int kt = 0; kt < 2; ++kt) {
        suma[kt] += __shfl_xor(suma[kt], 16);
        suma[kt] += __shfl_xor(suma[kt], 32);
    }

    // cross-wave log-tree reduction, aliasing the staging LDS as fp32 buffers
    float* vbuf = (float*)smem;
    __syncthreads();
#pragma unroll
    for (int step = 2; step >= 1; step >>= 1) {
        if (wave >= step && wave < 2*step) {
            float* dst = vbuf + (wave - step) * (32 * VB_STRIDE);
#pragma unroll
            for (int kt = 0; kt < 2; ++kt)
#pragma unroll
                for (int ct = 0; ct < 4; ++ct)
#pragma unroll
                    for (int r = 0; r < 4; ++r)
                        dst[(kt*16 + quad*4 + r)*VB_STRIDE + ct*16 + l15] = acc[kt][ct][r];
            if (lane < 16) {
                suma_buf[wave - step][lane]      = suma[0];
                suma_buf[wave - step][lane + 16] = suma[1];
            }
        }
        __syncthreads();
        if (wave < step) {
            const float* src = vbuf + wave * (32 * VB_STRIDE);
#pragma unroll
            for (int kt = 0; kt < 2; ++kt)
#pragma unroll
                for (int ct = 0; ct < 4; ++ct)
#pragma unroll
                    for (int r = 0; r < 4; ++r)
                        acc[kt][ct][r] += src[(kt*16 + quad*4 + r)*VB_STRIDE + ct*16 + l15];
            suma[0] += suma_buf[wave][l15];
            suma[1] += suma_buf[wave][l15 + 16];
        }
        __syncthreads();
    }

    // wave 0: write block partial {v (32x64), suma (32)} to workspace
    if (wave == 0) {
        float* wp = ws + (size_t)bid * WS_STRIDE;
#pragma unroll
        for (int kt = 0; kt < 2; ++kt)
#pragma unroll
            for (int r = 0; r < 4; ++r) {
                const int k = kt*16 + quad*4 + r;
#pragma unroll
                for (int ct = 0; ct < 4; ++ct)
                    wp[k*64 + ct*16 + l15] = acc[kt][ct][r];
            }
        if (lane < 16) {
            wp[2048 + lane]      = suma[0];   // lane holds total for k = lane
            wp[2048 + 16 + lane] = suma[1];   // and k = 16 + lane
        }
    }
}

// Kernel 2: combine the four N-quarters and apply  v - suma[k]*cent[k][c].
// 256 blocks x 512 threads, one float4 of output per thread (~10.5 MB traffic).
__global__ __launch_bounds__(512)
void netvlad_combine(const float* __restrict__ ws,
                     const float* __restrict__ cent,
                     float* __restrict__ out)
{
    const int m   = blockIdx.x;
    const int tid = threadIdx.x;
    const float* p0 = ws + (size_t)(4*m) * WS_STRIDE;
    const float* p1 = p0 + WS_STRIDE;
    const float* p2 = p1 + WS_STRIDE;
    const float* p3 = p2 + WS_STRIDE;

    const int k  = tid >> 4;          // 0..31
    const int c0 = (tid & 15) << 2;   // 0,4,...,60
    const float s = (p0[2048 + k] + p1[2048 + k]) + (p2[2048 + k] + p3[2048 + k]);

    const int off = k*64 + c0;
    const float4 v0 = *(const float4*)(p0 + off);
    const float4 v1 = *(const float4*)(p1 + off);
    const float4 v2 = *(const float4*)(p2 + off);
    const float4 v3 = *(const float4*)(p3 + off);
    const float4 cv = *(const float4*)(cent + off);
    float4 o;
    o.x = (v0.x + v1.x) + (v2.x + v3.x) - s * cv.x;
    o.y = (v0.y + v1.y) + (v2.y + v3.y) - s * cv.y;
    o.z = (v0.z + v1.z) + (v2.z + v3.z) - s * cv.z;
    o.w = (v0.w + v1.w) + (v2.w + v3.w) - s * cv.w;
    *(float4*)(out + (size_t)m * 2048 + off) = o;
}

extern "C" void kernel_launch(void* const* d_in, const int* in_sizes, int n_in,
                              void* d_out, int out_size, void* d_ws, size_t ws_size,
                              hipStream_t stream) {
    (void)in_sizes; (void)n_in; (void)out_size; (void)ws_size;
    const float* R = (const float*)d_in[0];   // R_seq (8,32,2048,64) fp32
    const float* W = (const float*)d_in[1];   // W (32,64) fp32
    const float* b = (const float*)d_in[2];   // b (32,) fp32
    const float* c = (const float*)d_in[3];   // centroids (32,64) fp32
    float* out = (float*)d_out;               // (8,32,32,64) fp32
    float* ws  = (float*)d_ws;                // 1024 * 2080 floats = 8.5 MB partials

    hipLaunchKernelGGL(netvlad_partial, dim3(1024), dim3(256), 0, stream, R, W, b, ws);
    hipLaunchKernelGGL(netvlad_combine, dim3(256), dim3(512), 0, stream, ws, c, out);
}

// Round 4
// 206.667 us; speedup vs baseline: 1.1048x; 1.1048x over previous
//
#include <hip/hip_runtime.h>
#include <stdint.h>

typedef __attribute__((ext_vector_type(8))) short bf16x8;
typedef __attribute__((ext_vector_type(4))) short bf16x4;
typedef __attribute__((ext_vector_type(4))) float f32x4;

#define WAVES 4
#define R_STRIDE 72                    // shorts; 144 B rows (16B aligned)
#define A_STRIDE 40                    // shorts; 80 B rows (16B aligned)
#define R_LDS_SHORTS (32 * R_STRIDE)   // 2304
#define A_LDS_SHORTS (32 * A_STRIDE)   // 1280
#define WAVE_LDS (R_LDS_SHORTS + A_LDS_SHORTS)  // 3584 shorts = 7168 B per wave
#define W_LDS_OFF (WAVES * WAVE_LDS)   // 14336 shorts; W bf16 tile lives here
#define SMEM_SHORTS (W_LDS_OFF + 2048) // 16384 shorts = 32768 B -> exactly 5 blocks/CU
#define VB_STRIDE 68                   // padded fp32 row stride for reduction buffers
#define NITER 2                        // 2 iters x 4 waves x 32 rows = 256 rows (1/8 of N)
#define WS_STRIDE 2080                 // floats per partial: 2048 v + 32 suma

static __device__ __forceinline__ unsigned short f2bf(float f) {
    union { float f; unsigned int i; } x; x.f = f;
    unsigned int i = x.i;
    return (unsigned short)((i + 0x7FFFu + ((i >> 16) & 1u)) >> 16);  // RNE
}

static __device__ __forceinline__ bf16x8 cvt8(float4 a, float4 b) {
    bf16x8 r;
    r[0] = (short)f2bf(a.x); r[1] = (short)f2bf(a.y);
    r[2] = (short)f2bf(a.z); r[3] = (short)f2bf(a.w);
    r[4] = (short)f2bf(b.x); r[5] = (short)f2bf(b.y);
    r[6] = (short)f2bf(b.z); r[7] = (short)f2bf(b.w);
    return r;
}

// Sum across the 16 lanes of a DPP row (all lanes end with the total).
static __device__ __forceinline__ float row_sum16(float x) {
    union fi { float f; int i; };
    fi a, b; a.f = x;
    b.i = __builtin_amdgcn_mov_dpp(a.i, 0x128, 0xf, 0xf, false); a.f += b.f;
    b.i = __builtin_amdgcn_mov_dpp(a.i, 0x124, 0xf, 0xf, false); a.f += b.f;
    b.i = __builtin_amdgcn_mov_dpp(a.i, 0x122, 0xf, 0xf, false); a.f += b.f;
    b.i = __builtin_amdgcn_mov_dpp(a.i, 0x121, 0xf, 0xf, false); a.f += b.f;
    return a.f;
}

// DESIGN FOR 64 VGPRs: rounds 1-3 proved this toolchain's allocator squeezes
// these kernels to 64 VGPRs regardless of __launch_bounds__/waves_per_eu
// ((512,4),(256)+attr(4,4),(256,4) all -> 64 + ~63 dwords/thread scratch
// spill = 66 MB/dispatch extra HBM writes). So: true live set is cut to
// ~64-70 by (a) evicting the 16-VGPR persistent W fragments to a 4 KB LDS
// tile (XOR-swizzled, bank-balanced reads), (b) per-s processing halving
// af/d1 transients. LDS = exactly 32 KiB/block -> 5 blocks/CU resident.
// (256,2) budget (the only shape ever observed honored, round 0) is kept:
// if honored -> 0 spill at ~80 regs; if squeezed to 64 -> spill ~0-6 slots.
__global__ __launch_bounds__(256, 2)
void netvlad_partial(const float* __restrict__ R,
                     const float* __restrict__ W,
                     const float* __restrict__ bias,
                     float* __restrict__ ws)
{
    __shared__ short smem[SMEM_SHORTS];   // 32768 B

    const int tid  = threadIdx.x;
    const int wave = tid >> 6;
    const int lane = tid & 63;
    const int l15  = lane & 15;
    const int quad = lane >> 4;
    const int bid  = blockIdx.x;
    const int m    = bid >> 3;
    const int h    = bid & 7;

    short* r_lds = smem + wave * WAVE_LDS;
    short* a_lds = r_lds + R_LDS_SHORTS;
    short* w_lds = smem + W_LDS_OFF;

    const float* Rm = R + ((size_t)m * 2048 + (size_t)h * 256) * 64;

    // Stage W (32x64) as bf16 into shared LDS. Every wave writes the full
    // tile with IDENTICAL data -> benign write-write race, no barrier needed
    // (each wave's reads are ordered after its own writes via lgkmcnt).
    // Swizzle: shorts addr = k*64 + (c ^ ((k&7)<<3)). Fragment reads
    // (8 shorts at c0 multiple of 8) stay contiguous/16B-aligned; per
    // ds_read_b128 every bank gets exactly 8 accesses = the 8-cycle floor.
#pragma unroll
    for (int kt = 0; kt < 2; ++kt)
#pragma unroll
        for (int cc = 0; cc < 2; ++cc) {
            const int k = kt*16 + l15;
            const int c = cc*32 + quad*8;
            const float* wp = W + k*64 + c;
            bf16x8 wv = cvt8(*(const float4*)wp, *(const float4*)(wp + 4));
            *(bf16x8*)(w_lds + k*64 + (c ^ ((k & 7) << 3))) = wv;
        }

    float bval[2];
    bval[0] = bias[l15];
    bval[1] = bias[16 + l15];

    f32x4 acc[2][4];   // v accumulator tiles [ktile][ctile], D-layout
#pragma unroll
    for (int kt = 0; kt < 2; ++kt)
#pragma unroll
        for (int ct = 0; ct < 4; ++ct)
            acc[kt][ct] = (f32x4){0.f, 0.f, 0.f, 0.f};
    float suma[2] = {0.f, 0.f};

#pragma unroll 1
    for (int it = 0; it < NITER; ++it) {
        const int n0 = it * (WAVES * 32) + wave * 32;

        // per-s: load+cvt+stage -> GEMM1 -> softmax (halves transient regs)
#pragma unroll
        for (int s = 0; s < 2; ++s) {
            const int g = (s*2 + (l15 >> 3)) & 3;          // (n>>3)&3 for n=s*16+l15
            bf16x8 af0, af1;
            {
                const float* rp = Rm + (size_t)(n0 + s*16 + l15)*64 + quad*8;
                af0 = cvt8(*(const float4*)rp, *(const float4*)(rp + 4));
                *(bf16x8*)(r_lds + (s*16 + l15)*R_STRIDE + ((quad*8) ^ (g << 4))) = af0;
            }
            {
                const float* rp = Rm + (size_t)(n0 + s*16 + l15)*64 + 32 + quad*8;
                af1 = cvt8(*(const float4*)rp, *(const float4*)(rp + 4));
                *(bf16x8*)(r_lds + (s*16 + l15)*R_STRIDE + ((32 + quad*8) ^ (g << 4))) = af1;
            }

            // GEMM1 for this s: W fragments re-read from LDS per kt (transient)
            f32x4 d1s[2];
#pragma unroll
            for (int kt = 0; kt < 2; ++kt) {
                const int k = kt*16 + l15;
                const bf16x8 w0 = *(const bf16x8*)(w_lds + k*64 + ((quad*8)      ^ ((k & 7) << 3)));
                const bf16x8 w1 = *(const bf16x8*)(w_lds + k*64 + ((32 + quad*8) ^ ((k & 7) << 3)));
                f32x4 d = (f32x4){0.f, 0.f, 0.f, 0.f};
                d = __builtin_amdgcn_mfma_f32_16x16x32_bf16(af0, w0, d, 0, 0, 0);
                d = __builtin_amdgcn_mfma_f32_16x16x32_bf16(af1, w1, d, 0, 0, 0);
                d1s[kt] = d;
            }

            // softmax over k (row = s*16 + quad*4 + r, k = kt*16 + l15)
            bf16x4 p0, p1;
            float a0s = 0.f, a1s = 0.f;
#pragma unroll
            for (int r = 0; r < 4; ++r) {
                float l0 = d1s[0][r] + bval[0];
                float l1 = d1s[1][r] + bval[1];
                float e0 = __expf(l0);
                float e1 = __expf(l1);
                float ss = row_sum16(e0 + e1);             // VALU DPP, off the LDS pipe
                float rs = __builtin_amdgcn_rcpf(ss);
                float a0 = e0 * rs, a1 = e1 * rs;
                a0s += a0; a1s += a1;
                p0[r] = (short)f2bf(a0);
                p1[r] = (short)f2bf(a1);
            }
            suma[0] += a0s; suma[1] += a1s;
            // a_lds[k][n] (n contiguous): 4 consecutive n per lane -> 8 B write
            *(bf16x4*)(a_lds + l15*A_STRIDE        + s*16 + quad*4) = p0;
            *(bf16x4*)(a_lds + (16 + l15)*A_STRIDE + s*16 + quad*4) = p1;
        }

        // A2 fragments: A[m=k][kdim=n] -> contiguous 16 B from a_lds
        bf16x8 a2[2];
#pragma unroll
        for (int kt = 0; kt < 2; ++kt)
            a2[kt] = *(bf16x8*)(a_lds + (kt*16 + l15)*A_STRIDE + quad*8);

        // GEMM2: v += a^T r ; B[kdim=n][col=c] gathered from swizzled r_lds.
        // element (n=quad*8+j, c=ct*16+l15) lives at n*R_STRIDE + (ct^quad)*16 + l15
#pragma unroll
        for (int ct = 0; ct < 4; ++ct) {
            const short* bp = r_lds + (quad*8)*R_STRIDE + ((ct ^ quad) << 4) + l15;
            bf16x8 b2;
#pragma unroll
            for (int j = 0; j < 8; ++j)
                b2[j] = bp[j*R_STRIDE];
#pragma unroll
            for (int kt = 0; kt < 2; ++kt)
                acc[kt][ct] = __builtin_amdgcn_mfma_f32_16x16x32_bf16(a2[kt], b2, acc[kt][ct], 0, 0, 0);
        }
    }

    // suma held per-lane for k = l15 (+16): fold the 4 quads together
#pragma unroll
    for (int kt = 0; kt < 2; ++kt) {
        suma[kt] += __shfl_xor(suma[kt], 16);
        suma[kt] += __shfl_xor(suma[kt], 32);
    }

    // cross-wave log-tree reduction. vbuf aliases the (dead) r/a staging LDS;
    // suma_buf aliases the (dead) W region. Both are safe after syncthreads.
    float* vbuf = (float*)smem;
    float* suma_buf = (float*)(smem + W_LDS_OFF);   // [2][32] floats, 256 B
    __syncthreads();
#pragma unroll
    for (int step = 2; step >= 1; step >>= 1) {
        if (wave >= step && wave < 2*step) {
            float* dst = vbuf + (wave - step) * (32 * VB_STRIDE);
#pragma unroll
            for (int kt = 0; kt < 2; ++kt)
#pragma unroll
                for (int ct = 0; ct < 4; ++ct)
#pragma unroll
                    for (int r = 0; r < 4; ++r)
                        dst[(kt*16 + quad*4 + r)*VB_STRIDE + ct*16 + l15] = acc[kt][ct][r];
            if (lane < 16) {
                suma_buf[(wave - step)*32 + lane]      = suma[0];
                suma_buf[(wave - step)*32 + lane + 16] = suma[1];
            }
        }
        __syncthreads();
        if (wave < step) {
            const float* src = vbuf + wave * (32 * VB_STRIDE);
#pragma unroll
            for (int kt = 0; kt < 2; ++kt)
#pragma unroll
                for (int ct = 0; ct < 4; ++ct)
#pragma unroll
                    for (int r = 0; r < 4; ++r)
                        acc[kt][ct][r] += src[(kt*16 + quad*4 + r)*VB_STRIDE + ct*16 + l15];
            suma[0] += suma_buf[wave*32 + l15];
            suma[1] += suma_buf[wave*32 + l15 + 16];
        }
        __syncthreads();
    }

    // wave 0: write block partial {v (32x64), suma (32)} to workspace
    if (wave == 0) {
        float* wp = ws + (size_t)bid * WS_STRIDE;
#pragma unroll
        for (int kt = 0; kt < 2; ++kt)
#pragma unroll
            for (int r = 0; r < 4; ++r) {
                const int k = kt*16 + quad*4 + r;
#pragma unroll
                for (int ct = 0; ct < 4; ++ct)
                    wp[k*64 + ct*16 + l15] = acc[kt][ct][r];
            }
        if (lane < 16) {
            wp[2048 + lane]      = suma[0];   // lane holds total for k = lane
            wp[2048 + 16 + lane] = suma[1];   // and k = 16 + lane
        }
    }
}

// Kernel 2: combine the eight N-slices and apply  v - suma[k]*cent[k][c].
// 256 blocks x 512 threads, one float4 of output per thread (~19 MB traffic).
__global__ __launch_bounds__(512)
void netvlad_combine(const float* __restrict__ ws,
                     const float* __restrict__ cent,
                     float* __restrict__ out)
{
    const int m   = blockIdx.x;
    const int tid = threadIdx.x;
    const float* pb = ws + (size_t)(8*m) * WS_STRIDE;

    const int k  = tid >> 4;          // 0..31
    const int c0 = (tid & 15) << 2;   // 0,4,...,60
    const int off = k*64 + c0;

    float s = 0.f;
    float4 v = {0.f, 0.f, 0.f, 0.f};
#pragma unroll
    for (int i = 0; i < 8; ++i) {
        const float* p = pb + (size_t)i * WS_STRIDE;
        s += p[2048 + k];
        const float4 vi = *(const float4*)(p + off);
        v.x += vi.x; v.y += vi.y; v.z += vi.z; v.w += vi.w;
    }

    const float4 cv = *(const float4*)(cent + off);
    float4 o;
    o.x = v.x - s * cv.x;
    o.y = v.y - s * cv.y;
    o.z = v.z - s * cv.z;
    o.w = v.w - s * cv.w;
    *(float4*)(out + (size_t)m * 2048 + off) = o;
}

extern "C" void kernel_launch(void* const* d_in, const int* in_sizes, int n_in,
                              void* d_out, int out_size, void* d_ws, size_t ws_size,
                              hipStream_t stream) {
    (void)in_sizes; (void)n_in; (void)out_size; (void)ws_size;
    const float* R = (const float*)d_in[0];   // R_seq (8,32,2048,64) fp32
    const float* W = (const float*)d_in[1];   // W (32,64) fp32
    const float* b = (const float*)d_in[2];   // b (32,) fp32
    const float* c = (const float*)d_in[3];   // centroids (32,64) fp32
    float* out = (float*)d_out;               // (8,32,32,64) fp32
    float* ws  = (float*)d_ws;                // 2048 * 2080 floats = 17 MB partials

    hipLaunchKernelGGL(netvlad_partial, dim3(2048), dim3(256), 0, stream, R, W, b, ws);
    hipLaunchKernelGGL(netvlad_combine, dim3(256), dim3(512), 0, stream, ws, c, out);
}